// Round 1
// baseline (93.357 us; speedup 1.0000x reference)
//
#include <hip/hip_runtime.h>

#define HDIM 64
#define CELLS 16
#define WPB 4                      // waves per block (256 threads)
#define PV (CELLS * HDIM + CELLS)  // 1040 floats per partial: 16x64 grid sums + 16 counts

// ---------------------------------------------------------------------------
// Kernel 1: per-block partial social pooling.
// Each wave: lanes read 64 agents' positions (float2, coalesced), compute cell
// id (or -1), then broadcast each agent's cell via __shfl; for masked agents
// the whole wave loads the 256B all_h row (lane = dim) and accumulates into a
// per-wave LDS [16][64] accumulator (bank = lane%32 -> 2-way, conflict-free).
// ---------------------------------------------------------------------------
__global__ void __launch_bounds__(256) k_pool(
    const float* __restrict__ all_h, const float2* __restrict__ pos2,
    const int* __restrict__ idxp, float* __restrict__ partial,
    int N, int nwaves)
{
    __shared__ float acc[WPB][CELLS * HDIM];  // 16 KB
    __shared__ float cnt[WPB][CELLS];
    const int tid  = threadIdx.x;
    const int wave = tid >> 6;
    const int lane = tid & 63;

    for (int v = tid; v < WPB * CELLS * HDIM; v += 256) ((float*)acc)[v] = 0.0f;
    if (tid < WPB * CELLS) ((float*)cnt)[tid] = 0.0f;
    __syncthreads();

    const int    idx0 = idxp[0];
    const float2 p0   = pos2[idx0];
    const int    gw   = blockIdx.x * WPB + wave;
    float* __restrict__ accw = acc[wave];

    for (int base = gw * 64; base < N; base += nwaves * 64) {
        const int a = base + lane;
        int cellid = -1;
        if (a < N && a != idx0) {
            const float2 p = pos2[a];
            const float dx = p.x - p0.x;
            const float dy = p.y - p0.y;
            if (fmaxf(fabsf(dx), fabsf(dy)) <= 4.0f) {
                // mirror reference: floor((d/NB + 1)/2 * G), clip to [0, G-1]
                const float f0 = floorf((dx / 4.0f + 1.0f) / 2.0f * 4.0f);
                const float f1 = floorf((dy / 4.0f + 1.0f) / 2.0f * 4.0f);
                const int g0 = (int)fminf(fmaxf(f0, 0.0f), 3.0f);
                const int g1 = (int)fminf(fmaxf(f1, 0.0f), 3.0f);
                cellid = g1 * 4 + g0;
                atomicAdd(&cnt[wave][cellid], 1.0f);  // exact int-in-f32, order-invariant
            }
        }
        const float* __restrict__ rowp = all_h + (size_t)base * HDIM + lane;
        for (int j = 0; j < 64; ++j) {
            const int c = __shfl(cellid, j);   // wave-uniform
            if (c >= 0) {                      // uniform branch: skip unmasked rows
                accw[c * HDIM + lane] += rowp[(size_t)j * HDIM];
            }
        }
    }
    __syncthreads();

    float* __restrict__ outp = partial + (size_t)blockIdx.x * PV;
    for (int v = tid; v < CELLS * HDIM; v += 256)
        outp[v] = acc[0][v] + acc[1][v] + acc[2][v] + acc[3][v];
    if (tid < CELLS)
        outp[CELLS * HDIM + tid] = cnt[0][tid] + cnt[1][tid] + cnt[2][tid] + cnt[3][tid];
}

// ---------------------------------------------------------------------------
// Kernel 2: fold nbp partials -> 1040 final values. One value per wave,
// lane-strided + butterfly reduce (fixed order -> deterministic).
// ---------------------------------------------------------------------------
__global__ void __launch_bounds__(256) k_reduce(
    const float* __restrict__ partial, float* __restrict__ finalv, int nbp)
{
    const int wave = threadIdx.x >> 6;
    const int lane = threadIdx.x & 63;
    const int v = blockIdx.x * 4 + wave;
    if (v >= PV) return;
    float s = 0.0f;
    for (int b = lane; b < nbp; b += 64)
        s += partial[(size_t)b * PV + v];
    #pragma unroll
    for (int off = 32; off > 0; off >>= 1)
        s += __shfl_xor(s, off);
    if (lane == 0) finalv[v] = s;
}

// ---------------------------------------------------------------------------
// Kernel 3: pooled -> social -> 8 encoder + 12 decoder LSTM steps.
// Thread j owns gate row j. Precompute per-thread:
//   m1k[4]  = W_ih[j,0:64] @ W_in          (folds emb matvec)
//   gconst  = b_ih + b_hh + W_ih[j,0:64]@b_in + W_ih[j,64:128]@social
//   whh[64] = W_hh row in registers
// Per step: g = gconst + m1k.x + whh.h  (68 FMAs), exchange via LDS.
// ---------------------------------------------------------------------------
__global__ void __launch_bounds__(256) k_lstm(
    const float* __restrict__ finalv, const float* __restrict__ history,
    const float* __restrict__ W_in, const float* __restrict__ b_in,
    const float* __restrict__ W_ih, const float* __restrict__ b_ih,
    const float* __restrict__ W_hh, const float* __restrict__ b_hh,
    const float* __restrict__ W_sp, const float* __restrict__ b_sp,
    const float* __restrict__ W_out, const float* __restrict__ b_out,
    float* __restrict__ out)
{
    __shared__ __align__(16) float pooled[64];
    __shared__ __align__(16) float social[64];
    __shared__ __align__(16) float hl[64];
    __shared__ __align__(16) float cl[64];
    __shared__ float gl[256];
    __shared__ float xs[4];
    __shared__ float lp[2];
    __shared__ float dl[2];
    const int tid = threadIdx.x;

    if (tid < 64) {
        float p = 0.0f;
        #pragma unroll
        for (int c = 0; c < CELLS; ++c) {
            const float cc = finalv[CELLS * HDIM + c];
            p += finalv[c * HDIM + tid] / fmaxf(cc, 1.0f);
        }
        pooled[tid] = p;
    }
    __syncthreads();
    if (tid < 64) {
        float s = b_sp[tid];
        for (int k = 0; k < 64; ++k) s += pooled[k] * W_sp[tid * 64 + k];
        social[tid] = s;
        hl[tid] = 0.0f;
        cl[tid] = 0.0f;
    }
    if (tid < 2) lp[tid] = history[7 * 4 + tid];  // history[-1,:2]
    __syncthreads();

    float m1k[4] = {0.0f, 0.0f, 0.0f, 0.0f};
    float gconst = b_ih[tid] + b_hh[tid];
    for (int m = 0; m < 64; ++m) {
        const float w = W_ih[tid * 128 + m];
        m1k[0] += w * W_in[m * 4 + 0];
        m1k[1] += w * W_in[m * 4 + 1];
        m1k[2] += w * W_in[m * 4 + 2];
        m1k[3] += w * W_in[m * 4 + 3];
        gconst += w * b_in[m];
    }
    for (int k = 0; k < 64; ++k)
        gconst += W_ih[tid * 128 + 64 + k] * social[k];
    float whh[64];
    #pragma unroll
    for (int k = 0; k < 64; ++k) whh[k] = W_hh[tid * 64 + k];

    // -------- encoder: 8 steps over history --------
    for (int t = 0; t < 8; ++t) {
        __syncthreads();                       // prev h/c update visible
        if (tid < 4) xs[tid] = history[t * 4 + tid];
        __syncthreads();
        float g = gconst + m1k[0] * xs[0] + m1k[1] * xs[1] + m1k[2] * xs[2] + m1k[3] * xs[3];
        #pragma unroll
        for (int k = 0; k < 64; k += 4) {
            const float4 h4 = *(const float4*)&hl[k];
            g += whh[k] * h4.x + whh[k + 1] * h4.y + whh[k + 2] * h4.z + whh[k + 3] * h4.w;
        }
        gl[tid] = g;
        __syncthreads();
        if (tid < 64) {
            const float ig = 1.0f / (1.0f + expf(-gl[tid]));
            const float fg = 1.0f / (1.0f + expf(-gl[64 + tid]));
            const float gg = tanhf(gl[128 + tid]);
            const float og = 1.0f / (1.0f + expf(-gl[192 + tid]));
            const float cn = fg * cl[tid] + ig * gg;
            cl[tid] = cn;
            hl[tid] = og * tanhf(cn);
        }
    }

    // -------- decoder: 12 prediction steps --------
    for (int t = 0; t < 12; ++t) {
        __syncthreads();                       // h update visible
        if (tid < 2) {
            float d = b_out[tid];
            for (int k = 0; k < 64; ++k) d += W_out[tid * 64 + k] * hl[k];
            dl[tid] = d;
            out[t * 2 + tid] = d;              // preds[t] = delta
        }
        __syncthreads();
        if (tid < 2) {
            const float npos = lp[tid] + dl[tid];
            xs[tid] = npos;                    // lp + delta
            xs[2 + tid] = dl[tid] * 2.0f;      // vel = delta / 0.5
            lp[tid] = npos;
        }
        __syncthreads();
        float g = gconst + m1k[0] * xs[0] + m1k[1] * xs[1] + m1k[2] * xs[2] + m1k[3] * xs[3];
        #pragma unroll
        for (int k = 0; k < 64; k += 4) {
            const float4 h4 = *(const float4*)&hl[k];
            g += whh[k] * h4.x + whh[k + 1] * h4.y + whh[k + 2] * h4.z + whh[k + 3] * h4.w;
        }
        gl[tid] = g;
        __syncthreads();
        if (tid < 64) {
            const float ig = 1.0f / (1.0f + expf(-gl[tid]));
            const float fg = 1.0f / (1.0f + expf(-gl[64 + tid]));
            const float gg = tanhf(gl[128 + tid]);
            const float og = 1.0f / (1.0f + expf(-gl[192 + tid]));
            const float cn = fg * cl[tid] + ig * gg;
            cl[tid] = cn;
            hl[tid] = og * tanhf(cn);
        }
    }
}

extern "C" void kernel_launch(void* const* d_in, const int* in_sizes, int n_in,
                              void* d_out, int out_size, void* d_ws, size_t ws_size,
                              hipStream_t stream) {
    const float* history   = (const float*)d_in[0];
    const float* all_h     = (const float*)d_in[1];
    const float* positions = (const float*)d_in[2];
    const float* W_in  = (const float*)d_in[3];
    const float* b_in  = (const float*)d_in[4];
    const float* W_ih  = (const float*)d_in[5];
    const float* b_ih  = (const float*)d_in[6];
    const float* W_hh  = (const float*)d_in[7];
    const float* b_hh  = (const float*)d_in[8];
    const float* W_sp  = (const float*)d_in[9];
    const float* b_sp  = (const float*)d_in[10];
    const float* W_out = (const float*)d_in[11];
    const float* b_out = (const float*)d_in[12];
    const int*   idxp  = (const int*)d_in[13];
    const int N = in_sizes[2] / 2;

    float* ws      = (float*)d_ws;
    float* finalv  = ws;        // 1040 floats
    float* partial = ws + PV;   // nbp * 1040 floats

    long long avail = (long long)(ws_size / sizeof(float)) - PV;
    int nbp = 2048;             // 8 blocks/CU, whole grid co-resident
    if ((long long)nbp * PV > avail) nbp = (int)(avail / PV);
    if (nbp < 1) nbp = 1;

    k_pool<<<nbp, 256, 0, stream>>>(all_h, (const float2*)positions, idxp,
                                    partial, N, nbp * WPB);
    k_reduce<<<(PV + 3) / 4, 256, 0, stream>>>(partial, finalv, nbp);
    k_lstm<<<1, 256, 0, stream>>>(finalv, history, W_in, b_in, W_ih, b_ih,
                                  W_hh, b_hh, W_sp, b_sp, W_out, b_out,
                                  (float*)d_out);
}

// Round 2
// 75.745 us; speedup vs baseline: 1.2325x; 1.2325x over previous
//
#include <hip/hip_runtime.h>

#define HDIM 64
#define CELLS 16
#define WPB 4                      // waves per block (256 threads)
#define PV (CELLS * HDIM + CELLS)  // 1040 floats per partial: 16x64 grid sums + 16 counts

// ---------------------------------------------------------------------------
// Kernel 1: per-block partial social pooling (latency-depth version).
// Per 64-agent chunk: lanes compute cell ids from positions, compact masked
// rows into a per-wave LDS list via ballot+prefix-popcount, then process the
// list in batches of 8 rows: issue 8 independent global_load_dword (8 x 256B
// in flight per wave), then 8 LDS accumulates (lane = column, per-wave
// accumulator, banks 2-way aliased = free). No per-row shfl, no per-row branch.
// ---------------------------------------------------------------------------
__global__ void __launch_bounds__(256) k_pool(
    const float* __restrict__ all_h, const float2* __restrict__ pos2,
    const int* __restrict__ idxp, float* __restrict__ partial,
    int N, int nwaves)
{
    __shared__ float acc[WPB][CELLS * HDIM];  // 16 KB
    __shared__ float cnt[WPB][CELLS];
    __shared__ __align__(16) int lst[WPB][64];
    const int tid  = threadIdx.x;
    const int wave = tid >> 6;
    const int lane = tid & 63;

    for (int v = tid; v < WPB * CELLS * HDIM; v += 256) ((float*)acc)[v] = 0.0f;
    if (tid < WPB * CELLS) ((float*)cnt)[tid] = 0.0f;
    __syncthreads();

    const int    idx0 = idxp[0];
    const float2 p0   = pos2[idx0];
    const int    gw   = blockIdx.x * WPB + wave;
    float* __restrict__ accw = acc[wave];
    int*   __restrict__ lstw = lst[wave];

    for (int base = gw * 64; base < N; base += nwaves * 64) {
        const int a = base + lane;
        int cellid = -1;
        if (a < N && a != idx0) {
            const float2 p = pos2[a];
            const float dx = p.x - p0.x;
            const float dy = p.y - p0.y;
            if (fmaxf(fabsf(dx), fabsf(dy)) <= 4.0f) {
                // mirror reference: floor((d/NB + 1)/2 * G), clip to [0, G-1]
                const float f0 = floorf((dx / 4.0f + 1.0f) / 2.0f * 4.0f);
                const float f1 = floorf((dy / 4.0f + 1.0f) / 2.0f * 4.0f);
                const int g0 = (int)fminf(fmaxf(f0, 0.0f), 3.0f);
                const int g1 = (int)fminf(fmaxf(f1, 0.0f), 3.0f);
                cellid = g1 * 4 + g0;
                atomicAdd(&cnt[wave][cellid], 1.0f);  // exact int-in-f32, order-invariant
            }
        }
        // ---- compact masked rows into per-wave list (lane order, determ.) ----
        const unsigned long long mask  = __ballot(cellid >= 0);
        const int                M     = __popcll(mask);
        const unsigned long long below = mask & ((1ULL << lane) - 1ULL);
        if (cellid >= 0) lstw[__popcll(below)] = (lane << 4) | cellid;
        // per-wave LDS: write->read same wave is in-order; no barrier needed

        const float* __restrict__ rowp = all_h + (size_t)base * HDIM + lane;
        int r = 0;
        for (; r + 8 <= M; r += 8) {
            const int4 e0 = *(const int4*)&lstw[r];      // uniform addr: broadcast
            const int4 e1 = *(const int4*)&lstw[r + 4];
            // issue all 8 loads before any accumulate (8 x 256B in flight)
            const float v0 = rowp[(size_t)(e0.x >> 4) * HDIM];
            const float v1 = rowp[(size_t)(e0.y >> 4) * HDIM];
            const float v2 = rowp[(size_t)(e0.z >> 4) * HDIM];
            const float v3 = rowp[(size_t)(e0.w >> 4) * HDIM];
            const float v4 = rowp[(size_t)(e1.x >> 4) * HDIM];
            const float v5 = rowp[(size_t)(e1.y >> 4) * HDIM];
            const float v6 = rowp[(size_t)(e1.z >> 4) * HDIM];
            const float v7 = rowp[(size_t)(e1.w >> 4) * HDIM];
            accw[(e0.x & 15) * HDIM + lane] += v0;
            accw[(e0.y & 15) * HDIM + lane] += v1;
            accw[(e0.z & 15) * HDIM + lane] += v2;
            accw[(e0.w & 15) * HDIM + lane] += v3;
            accw[(e1.x & 15) * HDIM + lane] += v4;
            accw[(e1.y & 15) * HDIM + lane] += v5;
            accw[(e1.z & 15) * HDIM + lane] += v6;
            accw[(e1.w & 15) * HDIM + lane] += v7;
        }
        for (; r < M; ++r) {
            const int e = lstw[r];
            accw[(e & 15) * HDIM + lane] += rowp[(size_t)(e >> 4) * HDIM];
        }
    }
    __syncthreads();

    float* __restrict__ outp = partial + (size_t)blockIdx.x * PV;
    for (int v = tid; v < CELLS * HDIM; v += 256)
        outp[v] = acc[0][v] + acc[1][v] + acc[2][v] + acc[3][v];
    if (tid < CELLS)
        outp[CELLS * HDIM + tid] = cnt[0][tid] + cnt[1][tid] + cnt[2][tid] + cnt[3][tid];
}

// ---------------------------------------------------------------------------
// Kernel 2: fold nbp partials -> 1040 final values. One value per wave,
// lane-strided + butterfly reduce (fixed order -> deterministic).
// ---------------------------------------------------------------------------
__global__ void __launch_bounds__(256) k_reduce(
    const float* __restrict__ partial, float* __restrict__ finalv, int nbp)
{
    const int wave = threadIdx.x >> 6;
    const int lane = threadIdx.x & 63;
    const int v = blockIdx.x * 4 + wave;
    if (v >= PV) return;
    float s = 0.0f;
    for (int b = lane; b < nbp; b += 64)
        s += partial[(size_t)b * PV + v];
    #pragma unroll
    for (int off = 32; off > 0; off >>= 1)
        s += __shfl_xor(s, off);
    if (lane == 0) finalv[v] = s;
}

// ---------------------------------------------------------------------------
// Kernel 3: pooled -> social -> 8 encoder + 12 decoder LSTM steps.
// Thread j owns gate row j. Precompute per-thread:
//   m1k[4]  = W_ih[j,0:64] @ W_in          (folds emb matvec)
//   gconst  = b_ih + b_hh + W_ih[j,0:64]@b_in + W_ih[j,64:128]@social
//   whh[64] = W_hh row in registers (float4 loads)
// Per step: g = gconst + m1k.x + whh.h  (68 FMAs, 4 split chains).
// ---------------------------------------------------------------------------
__global__ void __launch_bounds__(256) k_lstm(
    const float* __restrict__ finalv, const float* __restrict__ history,
    const float* __restrict__ W_in, const float* __restrict__ b_in,
    const float* __restrict__ W_ih, const float* __restrict__ b_ih,
    const float* __restrict__ W_hh, const float* __restrict__ b_hh,
    const float* __restrict__ W_sp, const float* __restrict__ b_sp,
    const float* __restrict__ W_out, const float* __restrict__ b_out,
    float* __restrict__ out)
{
    __shared__ __align__(16) float pooled[64];
    __shared__ __align__(16) float social[64];
    __shared__ __align__(16) float hl[64];
    __shared__ __align__(16) float cl[64];
    __shared__ float gl[256];
    __shared__ float xs[4];
    __shared__ float lp[2];
    __shared__ float dl[2];
    const int tid = threadIdx.x;

    if (tid < 64) {
        float p = 0.0f;
        #pragma unroll
        for (int c = 0; c < CELLS; ++c) {
            const float cc = finalv[CELLS * HDIM + c];
            p += finalv[c * HDIM + tid] / fmaxf(cc, 1.0f);
        }
        pooled[tid] = p;
    }
    __syncthreads();
    if (tid < 64) {
        float s = b_sp[tid];
        for (int k = 0; k < 64; k += 4) {
            const float4 w4 = *(const float4*)&W_sp[tid * 64 + k];
            s += pooled[k] * w4.x + pooled[k + 1] * w4.y
               + pooled[k + 2] * w4.z + pooled[k + 3] * w4.w;
        }
        social[tid] = s;
        hl[tid] = 0.0f;
        cl[tid] = 0.0f;
    }
    if (tid < 2) lp[tid] = history[7 * 4 + tid];  // history[-1,:2]
    __syncthreads();

    float m1k[4] = {0.0f, 0.0f, 0.0f, 0.0f};
    float gconst = b_ih[tid] + b_hh[tid];
    for (int m = 0; m < 64; m += 4) {
        const float4 w4 = *(const float4*)&W_ih[tid * 128 + m];  // row is 512B-aligned
        const float4 a0 = *(const float4*)&W_in[m * 4];          // rows m..m+3 of W_in(64x4)
        const float4 a1 = *(const float4*)&W_in[(m + 1) * 4];
        const float4 a2 = *(const float4*)&W_in[(m + 2) * 4];
        const float4 a3 = *(const float4*)&W_in[(m + 3) * 4];
        m1k[0] += w4.x * a0.x + w4.y * a1.x + w4.z * a2.x + w4.w * a3.x;
        m1k[1] += w4.x * a0.y + w4.y * a1.y + w4.z * a2.y + w4.w * a3.y;
        m1k[2] += w4.x * a0.z + w4.y * a1.z + w4.z * a2.z + w4.w * a3.z;
        m1k[3] += w4.x * a0.w + w4.y * a1.w + w4.z * a2.w + w4.w * a3.w;
        gconst += w4.x * b_in[m] + w4.y * b_in[m + 1]
                + w4.z * b_in[m + 2] + w4.w * b_in[m + 3];
    }
    for (int k = 0; k < 64; k += 4) {
        const float4 w4 = *(const float4*)&W_ih[tid * 128 + 64 + k];
        gconst += w4.x * social[k] + w4.y * social[k + 1]
                + w4.z * social[k + 2] + w4.w * social[k + 3];
    }
    float whh[64];
    #pragma unroll
    for (int k = 0; k < 64; k += 4) {
        const float4 w4 = *(const float4*)&W_hh[tid * 64 + k];
        whh[k] = w4.x; whh[k + 1] = w4.y; whh[k + 2] = w4.z; whh[k + 3] = w4.w;
    }

    // -------- encoder: 8 steps over history --------
    for (int t = 0; t < 8; ++t) {
        __syncthreads();                       // prev h/c update visible
        if (tid < 4) xs[tid] = history[t * 4 + tid];
        __syncthreads();
        float g0 = gconst + m1k[0] * xs[0] + m1k[1] * xs[1];
        float g1 = m1k[2] * xs[2] + m1k[3] * xs[3];
        float g2 = 0.0f, g3 = 0.0f;
        #pragma unroll
        for (int k = 0; k < 64; k += 16) {
            const float4 a = *(const float4*)&hl[k];
            const float4 b = *(const float4*)&hl[k + 4];
            const float4 c = *(const float4*)&hl[k + 8];
            const float4 d = *(const float4*)&hl[k + 12];
            g0 += whh[k] * a.x + whh[k + 1] * a.y + whh[k + 2] * a.z + whh[k + 3] * a.w;
            g1 += whh[k + 4] * b.x + whh[k + 5] * b.y + whh[k + 6] * b.z + whh[k + 7] * b.w;
            g2 += whh[k + 8] * c.x + whh[k + 9] * c.y + whh[k + 10] * c.z + whh[k + 11] * c.w;
            g3 += whh[k + 12] * d.x + whh[k + 13] * d.y + whh[k + 14] * d.z + whh[k + 15] * d.w;
        }
        gl[tid] = (g0 + g1) + (g2 + g3);
        __syncthreads();
        if (tid < 64) {
            const float ig = 1.0f / (1.0f + expf(-gl[tid]));
            const float fg = 1.0f / (1.0f + expf(-gl[64 + tid]));
            const float gg = tanhf(gl[128 + tid]);
            const float og = 1.0f / (1.0f + expf(-gl[192 + tid]));
            const float cn = fg * cl[tid] + ig * gg;
            cl[tid] = cn;
            hl[tid] = og * tanhf(cn);
        }
    }

    // -------- decoder: 12 prediction steps --------
    for (int t = 0; t < 12; ++t) {
        __syncthreads();                       // h update visible
        if (tid < 2) {
            float d = b_out[tid];
            for (int k = 0; k < 64; k += 4) {
                const float4 w4 = *(const float4*)&W_out[tid * 64 + k];
                d += w4.x * hl[k] + w4.y * hl[k + 1] + w4.z * hl[k + 2] + w4.w * hl[k + 3];
            }
            dl[tid] = d;
            out[t * 2 + tid] = d;              // preds[t] = delta
        }
        __syncthreads();
        if (tid < 2) {
            const float npos = lp[tid] + dl[tid];
            xs[tid] = npos;                    // lp + delta
            xs[2 + tid] = dl[tid] * 2.0f;      // vel = delta / 0.5
            lp[tid] = npos;
        }
        __syncthreads();
        float g0 = gconst + m1k[0] * xs[0] + m1k[1] * xs[1];
        float g1 = m1k[2] * xs[2] + m1k[3] * xs[3];
        float g2 = 0.0f, g3 = 0.0f;
        #pragma unroll
        for (int k = 0; k < 64; k += 16) {
            const float4 a = *(const float4*)&hl[k];
            const float4 b = *(const float4*)&hl[k + 4];
            const float4 c = *(const float4*)&hl[k + 8];
            const float4 d = *(const float4*)&hl[k + 12];
            g0 += whh[k] * a.x + whh[k + 1] * a.y + whh[k + 2] * a.z + whh[k + 3] * a.w;
            g1 += whh[k + 4] * b.x + whh[k + 5] * b.y + whh[k + 6] * b.z + whh[k + 7] * b.w;
            g2 += whh[k + 8] * c.x + whh[k + 9] * c.y + whh[k + 10] * c.z + whh[k + 11] * c.w;
            g3 += whh[k + 12] * d.x + whh[k + 13] * d.y + whh[k + 14] * d.z + whh[k + 15] * d.w;
        }
        gl[tid] = (g0 + g1) + (g2 + g3);
        __syncthreads();
        if (tid < 64) {
            const float ig = 1.0f / (1.0f + expf(-gl[tid]));
            const float fg = 1.0f / (1.0f + expf(-gl[64 + tid]));
            const float gg = tanhf(gl[128 + tid]);
            const float og = 1.0f / (1.0f + expf(-gl[192 + tid]));
            const float cn = fg * cl[tid] + ig * gg;
            cl[tid] = cn;
            hl[tid] = og * tanhf(cn);
        }
    }
}

extern "C" void kernel_launch(void* const* d_in, const int* in_sizes, int n_in,
                              void* d_out, int out_size, void* d_ws, size_t ws_size,
                              hipStream_t stream) {
    const float* history   = (const float*)d_in[0];
    const float* all_h     = (const float*)d_in[1];
    const float* positions = (const float*)d_in[2];
    const float* W_in  = (const float*)d_in[3];
    const float* b_in  = (const float*)d_in[4];
    const float* W_ih  = (const float*)d_in[5];
    const float* b_ih  = (const float*)d_in[6];
    const float* W_hh  = (const float*)d_in[7];
    const float* b_hh  = (const float*)d_in[8];
    const float* W_sp  = (const float*)d_in[9];
    const float* b_sp  = (const float*)d_in[10];
    const float* W_out = (const float*)d_in[11];
    const float* b_out = (const float*)d_in[12];
    const int*   idxp  = (const int*)d_in[13];
    const int N = in_sizes[2] / 2;

    float* ws      = (float*)d_ws;
    float* finalv  = ws;        // 1040 floats
    float* partial = ws + PV;   // nbp * 1040 floats

    long long avail = (long long)(ws_size / sizeof(float)) - PV;
    int nbp = 2048;             // 8 blocks/CU, whole grid co-resident
    if ((long long)nbp * PV > avail) nbp = (int)(avail / PV);
    if (nbp < 1) nbp = 1;

    k_pool<<<nbp, 256, 0, stream>>>(all_h, (const float2*)positions, idxp,
                                    partial, N, nbp * WPB);
    k_reduce<<<(PV + 3) / 4, 256, 0, stream>>>(partial, finalv, nbp);
    k_lstm<<<1, 256, 0, stream>>>(finalv, history, W_in, b_in, W_ih, b_ih,
                                  W_hh, b_hh, W_sp, b_sp, W_out, b_out,
                                  (float*)d_out);
}

// Round 3
// 74.064 us; speedup vs baseline: 1.2605x; 1.0227x over previous
//
#include <hip/hip_runtime.h>

#define HDIM 64
#define CELLS 16
#define WPB 4                      // waves per block (256 threads)
#define PV (CELLS * HDIM + CELLS)  // 1040 floats: 16x64 grid sums + 16 counts

// ws layout (floats): [0,1040) finalv | [1040,2064) m1k | [2064,2320) gconst0
//                     [2320,2576) sink | [2576, ...) partials (nbp * PV)
#define WS_M1K   1040
#define WS_G0    2064
#define WS_SINK  2320
#define WS_PART  2576

// ---------------------------------------------------------------------------
// Kernel 1: per-block partial social pooling.
// Per 64-agent chunk: compute cell ids, compact masked rows into a per-wave
// LDS list (ballot + prefix popcount), then process in batches of 16 rows:
// 16 independent global_load_dword issued back-to-back (16 x 256B in flight
// per wave), then 16 LDS accumulates (lane = column, 2-way bank alias = free).
// ---------------------------------------------------------------------------
__global__ void __launch_bounds__(256) k_pool(
    const float* __restrict__ all_h, const float2* __restrict__ pos2,
    const int* __restrict__ idxp, float* __restrict__ partial,
    int N, int nwaves)
{
    __shared__ float acc[WPB][CELLS * HDIM];  // 16 KB
    __shared__ float cnt[WPB][CELLS];
    __shared__ __align__(16) int lst[WPB][64];
    const int tid  = threadIdx.x;
    const int wave = tid >> 6;
    const int lane = tid & 63;

    for (int v = tid; v < WPB * CELLS * HDIM; v += 256) ((float*)acc)[v] = 0.0f;
    if (tid < WPB * CELLS) ((float*)cnt)[tid] = 0.0f;
    __syncthreads();

    const int    idx0 = idxp[0];
    const float2 p0   = pos2[idx0];
    const int    gw   = blockIdx.x * WPB + wave;
    float* __restrict__ accw = acc[wave];
    int*   __restrict__ lstw = lst[wave];

    for (int base = gw * 64; base < N; base += nwaves * 64) {
        const int a = base + lane;
        int cellid = -1;
        if (a < N && a != idx0) {
            const float2 p = pos2[a];
            const float dx = p.x - p0.x;
            const float dy = p.y - p0.y;
            if (fmaxf(fabsf(dx), fabsf(dy)) <= 4.0f) {
                const float f0 = floorf((dx / 4.0f + 1.0f) / 2.0f * 4.0f);
                const float f1 = floorf((dy / 4.0f + 1.0f) / 2.0f * 4.0f);
                const int g0 = (int)fminf(fmaxf(f0, 0.0f), 3.0f);
                const int g1 = (int)fminf(fmaxf(f1, 0.0f), 3.0f);
                cellid = g1 * 4 + g0;
                atomicAdd(&cnt[wave][cellid], 1.0f);  // exact int-in-f32
            }
        }
        const unsigned long long mask  = __ballot(cellid >= 0);
        const int                M     = __popcll(mask);
        const unsigned long long below = mask & ((1ULL << lane) - 1ULL);
        if (cellid >= 0) lstw[__popcll(below)] = (lane << 4) | cellid;
        // same-wave LDS write->read is in-order; no barrier needed

        const float* __restrict__ rowp = all_h + (size_t)base * HDIM + lane;
        int r = 0;
        for (; r + 16 <= M; r += 16) {
            const int4 e0 = *(const int4*)&lstw[r];
            const int4 e1 = *(const int4*)&lstw[r + 4];
            const int4 e2 = *(const int4*)&lstw[r + 8];
            const int4 e3 = *(const int4*)&lstw[r + 12];
            const float v0  = rowp[(size_t)(e0.x >> 4) * HDIM];
            const float v1  = rowp[(size_t)(e0.y >> 4) * HDIM];
            const float v2  = rowp[(size_t)(e0.z >> 4) * HDIM];
            const float v3  = rowp[(size_t)(e0.w >> 4) * HDIM];
            const float v4  = rowp[(size_t)(e1.x >> 4) * HDIM];
            const float v5  = rowp[(size_t)(e1.y >> 4) * HDIM];
            const float v6  = rowp[(size_t)(e1.z >> 4) * HDIM];
            const float v7  = rowp[(size_t)(e1.w >> 4) * HDIM];
            const float v8  = rowp[(size_t)(e2.x >> 4) * HDIM];
            const float v9  = rowp[(size_t)(e2.y >> 4) * HDIM];
            const float v10 = rowp[(size_t)(e2.z >> 4) * HDIM];
            const float v11 = rowp[(size_t)(e2.w >> 4) * HDIM];
            const float v12 = rowp[(size_t)(e3.x >> 4) * HDIM];
            const float v13 = rowp[(size_t)(e3.y >> 4) * HDIM];
            const float v14 = rowp[(size_t)(e3.z >> 4) * HDIM];
            const float v15 = rowp[(size_t)(e3.w >> 4) * HDIM];
            accw[(e0.x & 15) * HDIM + lane] += v0;
            accw[(e0.y & 15) * HDIM + lane] += v1;
            accw[(e0.z & 15) * HDIM + lane] += v2;
            accw[(e0.w & 15) * HDIM + lane] += v3;
            accw[(e1.x & 15) * HDIM + lane] += v4;
            accw[(e1.y & 15) * HDIM + lane] += v5;
            accw[(e1.z & 15) * HDIM + lane] += v6;
            accw[(e1.w & 15) * HDIM + lane] += v7;
            accw[(e2.x & 15) * HDIM + lane] += v8;
            accw[(e2.y & 15) * HDIM + lane] += v9;
            accw[(e2.z & 15) * HDIM + lane] += v10;
            accw[(e2.w & 15) * HDIM + lane] += v11;
            accw[(e3.x & 15) * HDIM + lane] += v12;
            accw[(e3.y & 15) * HDIM + lane] += v13;
            accw[(e3.z & 15) * HDIM + lane] += v14;
            accw[(e3.w & 15) * HDIM + lane] += v15;
        }
        for (; r + 8 <= M; r += 8) {
            const int4 e0 = *(const int4*)&lstw[r];
            const int4 e1 = *(const int4*)&lstw[r + 4];
            const float v0 = rowp[(size_t)(e0.x >> 4) * HDIM];
            const float v1 = rowp[(size_t)(e0.y >> 4) * HDIM];
            const float v2 = rowp[(size_t)(e0.z >> 4) * HDIM];
            const float v3 = rowp[(size_t)(e0.w >> 4) * HDIM];
            const float v4 = rowp[(size_t)(e1.x >> 4) * HDIM];
            const float v5 = rowp[(size_t)(e1.y >> 4) * HDIM];
            const float v6 = rowp[(size_t)(e1.z >> 4) * HDIM];
            const float v7 = rowp[(size_t)(e1.w >> 4) * HDIM];
            accw[(e0.x & 15) * HDIM + lane] += v0;
            accw[(e0.y & 15) * HDIM + lane] += v1;
            accw[(e0.z & 15) * HDIM + lane] += v2;
            accw[(e0.w & 15) * HDIM + lane] += v3;
            accw[(e1.x & 15) * HDIM + lane] += v4;
            accw[(e1.y & 15) * HDIM + lane] += v5;
            accw[(e1.z & 15) * HDIM + lane] += v6;
            accw[(e1.w & 15) * HDIM + lane] += v7;
        }
        for (; r < M; ++r) {
            const int e = lstw[r];
            accw[(e & 15) * HDIM + lane] += rowp[(size_t)(e >> 4) * HDIM];
        }
    }
    __syncthreads();

    float* __restrict__ outp = partial + (size_t)blockIdx.x * PV;
    for (int v = tid; v < CELLS * HDIM; v += 256)
        outp[v] = acc[0][v] + acc[1][v] + acc[2][v] + acc[3][v];
    if (tid < CELLS)
        outp[CELLS * HDIM + tid] = cnt[0][tid] + cnt[1][tid] + cnt[2][tid] + cnt[3][tid];
}

// ---------------------------------------------------------------------------
// Kernel 2: blocks 0..259 fold nbp partials -> 1040 final values.
// Block 260 (concurrent, hidden under the reduce): precompute the LSTM's
// input-weight folds m1k = W_ih[:, 0:64] @ W_in and
// gconst0 = b_ih + b_hh + W_ih[:,0:64] @ b_in into ws, and warm
// W_ih-right / W_hh / W_sp / W_out into L2 for k_lstm.
// ---------------------------------------------------------------------------
__global__ void __launch_bounds__(256) k_reduce(
    const float* __restrict__ partial, float* __restrict__ ws,
    const float* __restrict__ W_in, const float* __restrict__ b_in,
    const float* __restrict__ W_ih, const float* __restrict__ b_ih,
    const float* __restrict__ W_hh, const float* __restrict__ b_hh,
    const float* __restrict__ W_sp, const float* __restrict__ W_out,
    int nbp)
{
    const int tid = threadIdx.x;
    if (blockIdx.x < 260) {
        const int wave = tid >> 6;
        const int lane = tid & 63;
        const int v = blockIdx.x * 4 + wave;
        if (v >= PV) return;
        float s = 0.0f;
        for (int b = lane; b < nbp; b += 64)
            s += partial[(size_t)b * PV + v];
        #pragma unroll
        for (int off = 32; off > 0; off >>= 1)
            s += __shfl_xor(s, off);
        if (lane == 0) ws[v] = s;
        return;
    }
    // ---- prep block ----
    float m0 = 0.0f, m1 = 0.0f, m2 = 0.0f, m3 = 0.0f;
    float gc = b_ih[tid] + b_hh[tid];
    for (int m = 0; m < 64; m += 4) {
        const float4 w4 = *(const float4*)&W_ih[tid * 128 + m];
        const float4 a0 = *(const float4*)&W_in[m * 4];
        const float4 a1 = *(const float4*)&W_in[(m + 1) * 4];
        const float4 a2 = *(const float4*)&W_in[(m + 2) * 4];
        const float4 a3 = *(const float4*)&W_in[(m + 3) * 4];
        m0 += w4.x * a0.x + w4.y * a1.x + w4.z * a2.x + w4.w * a3.x;
        m1 += w4.x * a0.y + w4.y * a1.y + w4.z * a2.y + w4.w * a3.y;
        m2 += w4.x * a0.z + w4.y * a1.z + w4.z * a2.z + w4.w * a3.z;
        m3 += w4.x * a0.w + w4.y * a1.w + w4.z * a2.w + w4.w * a3.w;
        gc += w4.x * b_in[m] + w4.y * b_in[m + 1]
            + w4.z * b_in[m + 2] + w4.w * b_in[m + 3];
    }
    float4 mv; mv.x = m0; mv.y = m1; mv.z = m2; mv.w = m3;
    *(float4*)&ws[WS_M1K + tid * 4] = mv;
    ws[WS_G0 + tid] = gc;
    // L2 warm for k_lstm (sink values are never read back)
    float warm = 0.0f;
    for (int k = 0; k < 64; k += 4) {
        const float4 a = *(const float4*)&W_ih[tid * 128 + 64 + k];
        const float4 b = *(const float4*)&W_hh[tid * 64 + k];
        warm += a.x + a.y + a.z + a.w + b.x + b.y + b.z + b.w;
    }
    for (int k = 0; k < 16; k += 4) {
        const float4 c = *(const float4*)&W_sp[tid * 16 + k];
        warm += c.x + c.y + c.z + c.w;
    }
    warm += W_out[tid & 127];
    ws[WS_SINK + tid] = warm;
}

// ---------------------------------------------------------------------------
// Kernel 3: pooled -> social -> 8 encoder + 12 decoder LSTM steps.
// m1k/gconst0 come precomputed from ws; weights are L2-warm.
// Encoder: 2 barriers/step (history preloaded in LDS).
// Decoder: delta via wave-0 butterfly reduce (W_out cached in regs), 3/step.
// ---------------------------------------------------------------------------
__global__ void __launch_bounds__(256) k_lstm(
    const float* __restrict__ ws, const float* __restrict__ history,
    const float* __restrict__ W_ih, const float* __restrict__ W_hh,
    const float* __restrict__ W_sp, const float* __restrict__ b_sp,
    const float* __restrict__ W_out, const float* __restrict__ b_out,
    float* __restrict__ out)
{
    __shared__ __align__(16) float pooled[64];
    __shared__ __align__(16) float social[64];
    __shared__ __align__(16) float hl[64];
    __shared__ __align__(16) float cl[64];
    __shared__ float gl[256];
    __shared__ __align__(16) float histl[32];
    __shared__ float xs[4];
    __shared__ float lp[2];
    const int tid = threadIdx.x;

    if (tid < 32) histl[tid] = history[tid];
    if (tid < 64) {
        float p = 0.0f;
        #pragma unroll
        for (int c = 0; c < CELLS; ++c) {
            const float cc = ws[CELLS * HDIM + c];
            p += ws[c * HDIM + tid] / fmaxf(cc, 1.0f);
        }
        pooled[tid] = p;
    }
    __syncthreads();
    if (tid < 64) {
        float s = b_sp[tid];
        for (int k = 0; k < 64; k += 4) {
            const float4 w4 = *(const float4*)&W_sp[tid * 64 + k];
            s += pooled[k] * w4.x + pooled[k + 1] * w4.y
               + pooled[k + 2] * w4.z + pooled[k + 3] * w4.w;
        }
        social[tid] = s;
        hl[tid] = 0.0f;
        cl[tid] = 0.0f;
    }
    if (tid == 0) { lp[0] = histl[28]; lp[1] = histl[29]; }
    __syncthreads();

    const float4 mv = *(const float4*)&ws[WS_M1K + tid * 4];
    float gconst = ws[WS_G0 + tid];
    for (int k = 0; k < 64; k += 4) {
        const float4 w4 = *(const float4*)&W_ih[tid * 128 + 64 + k];
        gconst += w4.x * social[k] + w4.y * social[k + 1]
                + w4.z * social[k + 2] + w4.w * social[k + 3];
    }
    float whh[64];
    #pragma unroll
    for (int k = 0; k < 64; k += 4) {
        const float4 w4 = *(const float4*)&W_hh[tid * 64 + k];
        whh[k] = w4.x; whh[k + 1] = w4.y; whh[k + 2] = w4.z; whh[k + 3] = w4.w;
    }
    // wave-0 caches for the decoder delta matvec
    float wout0 = 0.0f, wout1 = 0.0f, bo0 = 0.0f, bo1 = 0.0f;
    if (tid < 64) {
        wout0 = W_out[tid]; wout1 = W_out[64 + tid];
        bo0 = b_out[0]; bo1 = b_out[1];
    }
    __syncthreads();   // social/m1k setup done; hl/cl visible

    // -------- encoder: 8 steps over history (2 barriers/step) --------
    for (int t = 0; t < 8; ++t) {
        const float x0 = histl[t * 4 + 0], x1 = histl[t * 4 + 1];
        const float x2 = histl[t * 4 + 2], x3 = histl[t * 4 + 3];
        float g0 = gconst + mv.x * x0 + mv.y * x1;
        float g1 = mv.z * x2 + mv.w * x3;
        float g2 = 0.0f, g3 = 0.0f;
        #pragma unroll
        for (int k = 0; k < 64; k += 16) {
            const float4 a = *(const float4*)&hl[k];
            const float4 b = *(const float4*)&hl[k + 4];
            const float4 c = *(const float4*)&hl[k + 8];
            const float4 d = *(const float4*)&hl[k + 12];
            g0 += whh[k] * a.x + whh[k + 1] * a.y + whh[k + 2] * a.z + whh[k + 3] * a.w;
            g1 += whh[k + 4] * b.x + whh[k + 5] * b.y + whh[k + 6] * b.z + whh[k + 7] * b.w;
            g2 += whh[k + 8] * c.x + whh[k + 9] * c.y + whh[k + 10] * c.z + whh[k + 11] * c.w;
            g3 += whh[k + 12] * d.x + whh[k + 13] * d.y + whh[k + 14] * d.z + whh[k + 15] * d.w;
        }
        gl[tid] = (g0 + g1) + (g2 + g3);
        __syncthreads();
        if (tid < 64) {
            const float ig = 1.0f / (1.0f + expf(-gl[tid]));
            const float fg = 1.0f / (1.0f + expf(-gl[64 + tid]));
            const float gg = tanhf(gl[128 + tid]);
            const float og = 1.0f / (1.0f + expf(-gl[192 + tid]));
            const float cn = fg * cl[tid] + ig * gg;
            cl[tid] = cn;
            hl[tid] = og * tanhf(cn);
        }
        __syncthreads();
    }

    // -------- decoder: 12 prediction steps (3 barriers/step) --------
    for (int t = 0; t < 12; ++t) {
        if (tid < 64) {
            float s0 = wout0 * hl[tid];
            float s1 = wout1 * hl[tid];
            #pragma unroll
            for (int off = 32; off > 0; off >>= 1) {
                s0 += __shfl_xor(s0, off);
                s1 += __shfl_xor(s1, off);
            }
            if (tid == 0) {
                const float d0 = s0 + bo0, d1 = s1 + bo1;
                out[t * 2 + 0] = d0;
                out[t * 2 + 1] = d1;
                const float n0 = lp[0] + d0, n1 = lp[1] + d1;
                xs[0] = n0; xs[1] = n1;
                xs[2] = d0 * 2.0f; xs[3] = d1 * 2.0f;
                lp[0] = n0; lp[1] = n1;
            }
        }
        __syncthreads();
        const float x0 = xs[0], x1 = xs[1], x2 = xs[2], x3 = xs[3];
        float g0 = gconst + mv.x * x0 + mv.y * x1;
        float g1 = mv.z * x2 + mv.w * x3;
        float g2 = 0.0f, g3 = 0.0f;
        #pragma unroll
        for (int k = 0; k < 64; k += 16) {
            const float4 a = *(const float4*)&hl[k];
            const float4 b = *(const float4*)&hl[k + 4];
            const float4 c = *(const float4*)&hl[k + 8];
            const float4 d = *(const float4*)&hl[k + 12];
            g0 += whh[k] * a.x + whh[k + 1] * a.y + whh[k + 2] * a.z + whh[k + 3] * a.w;
            g1 += whh[k + 4] * b.x + whh[k + 5] * b.y + whh[k + 6] * b.z + whh[k + 7] * b.w;
            g2 += whh[k + 8] * c.x + whh[k + 9] * c.y + whh[k + 10] * c.z + whh[k + 11] * c.w;
            g3 += whh[k + 12] * d.x + whh[k + 13] * d.y + whh[k + 14] * d.z + whh[k + 15] * d.w;
        }
        gl[tid] = (g0 + g1) + (g2 + g3);
        __syncthreads();
        if (tid < 64) {
            const float ig = 1.0f / (1.0f + expf(-gl[tid]));
            const float fg = 1.0f / (1.0f + expf(-gl[64 + tid]));
            const float gg = tanhf(gl[128 + tid]);
            const float og = 1.0f / (1.0f + expf(-gl[192 + tid]));
            const float cn = fg * cl[tid] + ig * gg;
            cl[tid] = cn;
            hl[tid] = og * tanhf(cn);
        }
        __syncthreads();
    }
}

extern "C" void kernel_launch(void* const* d_in, const int* in_sizes, int n_in,
                              void* d_out, int out_size, void* d_ws, size_t ws_size,
                              hipStream_t stream) {
    const float* history   = (const float*)d_in[0];
    const float* all_h     = (const float*)d_in[1];
    const float* positions = (const float*)d_in[2];
    const float* W_in  = (const float*)d_in[3];
    const float* b_in  = (const float*)d_in[4];
    const float* W_ih  = (const float*)d_in[5];
    const float* b_ih  = (const float*)d_in[6];
    const float* W_hh  = (const float*)d_in[7];
    const float* b_hh  = (const float*)d_in[8];
    const float* W_sp  = (const float*)d_in[9];
    const float* b_sp  = (const float*)d_in[10];
    const float* W_out = (const float*)d_in[11];
    const float* b_out = (const float*)d_in[12];
    const int*   idxp  = (const int*)d_in[13];
    const int N = in_sizes[2] / 2;

    float* ws      = (float*)d_ws;
    float* partial = ws + WS_PART;

    long long avail = (long long)(ws_size / sizeof(float)) - WS_PART;
    int nbp = 2048;             // 8 blocks/CU, whole grid co-resident
    if ((long long)nbp * PV > avail) nbp = (int)(avail / PV);
    if (nbp < 1) nbp = 1;

    k_pool<<<nbp, 256, 0, stream>>>(all_h, (const float2*)positions, idxp,
                                    partial, N, nbp * WPB);
    k_reduce<<<261, 256, 0, stream>>>(partial, ws, W_in, b_in, W_ih, b_ih,
                                      W_hh, b_hh, W_sp, W_out, nbp);
    k_lstm<<<1, 256, 0, stream>>>(ws, history, W_ih, W_hh, W_sp, b_sp,
                                  W_out, b_out, (float*)d_out);
}